// Round 21
// baseline (108.345 us; speedup 1.0000x reference)
//
#include <hip/hip_runtime.h>

#define NNODES 100000
#define NREL 8
#define EMB 64
#define YDIM (NREL * EMB)            // 512
#define NSTRIPS (NNODES / 16)        // 6250, exact
#define GEMMB 3125                   // gemm blocks; exactly 2 strips each
#define GNODES 98                    // nodes per bucket (<=127 for 7-bit nloc)
#define NBUCK 1024                   // buckets: 4/CU exact for gather
#define SCHUNK 2048                  // edges per scatter block (512 thr)
#define CAPB 1280                    // slots per bucket; lambda=977, +9.7 sigma

typedef __attribute__((ext_vector_type(8))) short bf16x8;   // 8 bf16 (4 VGPRs)
typedef __attribute__((ext_vector_type(4))) float f32x4;
typedef __attribute__((ext_vector_type(4))) int   i32x4;    // for nontemporal 16B

__device__ inline unsigned short f2bf(float f) {
    union { float f; unsigned u; } v; v.f = f;
    return (unsigned short)((v.u + 0x7FFFu + ((v.u >> 16) & 1u)) >> 16);  // RNE
}
__device__ inline float bf2f(unsigned short u) {
    union { unsigned u; float f; } v; v.u = ((unsigned)u) << 16; return v.f;
}

// ---------------------------------------------------------------------------
// Init: per-bucket cursor = fixed region base
// ---------------------------------------------------------------------------
__global__ void k_init(int* __restrict__ cursor) {
    int t = blockIdx.x * blockDim.x + threadIdx.x;
    if (t < NBUCK) cursor[t] = t * CAPB;
}

// ---------------------------------------------------------------------------
// W prep (unchanged): pack W into MFMA A-fragment order.
// ---------------------------------------------------------------------------
__global__ void k_wprep(const float* __restrict__ W, unsigned short* __restrict__ wp) {
    int t = blockIdx.x * blockDim.x + threadIdx.x;   // 0..4095
    int lane = t & 63, ks = (t >> 6) & 1, ft = (t >> 7) & 3, rel = t >> 9;
    const float* src = W + rel * 4096 + (ks * 32 + (lane >> 4) * 8) * EMB
                       + ft * 16 + (lane & 15);
    bf16x8 o;
#pragma unroll
    for (int j = 0; j < 8; ++j) o[j] = (short)f2bf(src[j * EMB]);
    *reinterpret_cast<bf16x8*>(wp + (size_t)t * 8) = o;
}

// ---------------------------------------------------------------------------
// FAT kernel: blocks [0, sblk) = partitioned scatter (independent of GEMM,
// complementary traffic: ~13MB vs GEMM's 100MB write stream -> overlaps);
// blocks [sblk, sblk+GEMMB) = GEMM1, exactly 2 strips each.
// ---------------------------------------------------------------------------
__global__ __launch_bounds__(512) void k_main(const int* __restrict__ rows,
                                              const int* __restrict__ cols,
                                              int* __restrict__ cursor,
                                              int* __restrict__ keys,
                                              const float* __restrict__ x,
                                              const unsigned short* __restrict__ wp,
                                              unsigned short* __restrict__ y,
                                              int E, int sblk) {
    __shared__ __align__(16) char sm[33280];
    const int t = threadIdx.x;

    if ((int)blockIdx.x < sblk) {
        // ================= scatter part (512 thr, 2048 edges) =================
        int*  hist = (int*)sm;                 // 4 KB (1024 bins)
        int*  loff = (int*)(sm + 4096);        // 4 KB
        int*  dlt  = (int*)(sm + 8192);        // 4 KB
        int*  cur  = (int*)(sm + 12288);       // 4 KB
        int*  part = (int*)(sm + 16384);       // 8 ints (pad 64B)
        int2* stg  = (int2*)(sm + 16448);      // 16 KB
        const int base = blockIdx.x * SCHUNK;
        int m = E - base; if (m > SCHUNK) m = SCHUNK;

        hist[t] = 0; hist[t + 512] = 0; cur[t] = 0; cur[t + 512] = 0;
        __syncthreads();

        int key[4], bk[4];
#pragma unroll
        for (int q = 0; q < 4; ++q) {
            int i = t + q * 512;
            bk[q] = -1;
            if (i < m) {
                int row = rows[base + i];
                int c   = cols[base + i];
                int r = row / NNODES;          // magic-mul
                int n = row - r * NNODES;
                bk[q]  = n / GNODES;           // magic-mul
                int nloc = n - bk[q] * GNODES;
                key[q] = (c << 3) | r | (nloc << 20);
                atomicAdd(&hist[bk[q]], 1);
            }
        }
        __syncthreads();

        // 2-barrier scan over 1024 bins (2/thread presum + wave shfl-scan)
        const int lane = t & 63, wid = t >> 6;
        int v0 = hist[2 * t], v1 = hist[2 * t + 1];
        int v = v0 + v1;
        int inc = v;
#pragma unroll
        for (int d = 1; d < 64; d <<= 1) { int u = __shfl_up(inc, d); if (lane >= d) inc += u; }
        if (lane == 63) part[wid] = inc;
        __syncthreads();
        int woff = 0;
        for (int i = 0; i < wid; ++i) woff += part[i];
        int excl = woff + inc - v;
        loff[2 * t]     = excl;
        loff[2 * t + 1] = excl + v0;
        int gb = (v0 > 0) ? atomicAdd(&cursor[2 * t], v0) : 0;
        dlt[2 * t] = gb - excl;
        gb = (v1 > 0) ? atomicAdd(&cursor[2 * t + 1], v1) : 0;
        dlt[2 * t + 1] = gb - (excl + v0);
        __syncthreads();

#pragma unroll
        for (int q = 0; q < 4; ++q) {
            if (bk[q] >= 0) {
                int p = loff[bk[q]] + atomicAdd(&cur[bk[q]], 1);
                stg[p] = make_int2(key[q], dlt[bk[q]]);
            }
        }
        __syncthreads();

        for (int i = t; i < m; i += 512) {
            int2 s = stg[i];
            keys[s.y + i] = s.x;
        }
        return;
    }

    // ==================== gemm part (round-19 verified) ====================
    char* tile0 = sm;                          // 2 x 16 KB double buffer
    const int lane = t & 63;
    const int rel  = t >> 6;                   // wave id = relation
    const int fl   = lane & 15;                // A row (f_local) == B col (c_local)
    const int kgrp = lane >> 4;                // k-group 0..3

    bf16x8 wfrag[4][2];
#pragma unroll
    for (int ft = 0; ft < 4; ++ft)
#pragma unroll
        for (int ks = 0; ks < 2; ++ks)
            wfrag[ft][ks] = *reinterpret_cast<const bf16x8*>(
                wp + (size_t)((rel * 4 + ft) * 2 + ks) * 512 + lane * 8);

    const int wbase = (fl << 10) + (rel << 7) + (kgrp << 3);
    const int wswz  = (fl & 7) << 4;
    int b = 0;

    int strip = blockIdx.x - sblk;
    const float* xp = x + (size_t)(strip * 16 + fl) * EMB + kgrp * 8;
    f32x4 xa0 = *reinterpret_cast<const f32x4*>(xp);
    f32x4 xa1 = *reinterpret_cast<const f32x4*>(xp + 4);
    f32x4 xa2 = *reinterpret_cast<const f32x4*>(xp + 32);
    f32x4 xa3 = *reinterpret_cast<const f32x4*>(xp + 36);

    while (strip < NSTRIPS) {
        const int next = strip + GEMMB;
        f32x4 xn0 = xa0, xn1 = xa1, xn2 = xa2, xn3 = xa3;
        if (next < NSTRIPS) {              // prefetch next strip's x rows
            const float* xq = x + (size_t)(next * 16 + fl) * EMB + kgrp * 8;
            xn0 = *reinterpret_cast<const f32x4*>(xq);
            xn1 = *reinterpret_cast<const f32x4*>(xq + 4);
            xn2 = *reinterpret_cast<const f32x4*>(xq + 32);
            xn3 = *reinterpret_cast<const f32x4*>(xq + 36);
        }

        bf16x8 B0, B1;
#pragma unroll
        for (int j = 0; j < 4; ++j) {
            B0[j] = (short)f2bf(xa0[j]);  B0[j + 4] = (short)f2bf(xa1[j]);
            B1[j] = (short)f2bf(xa2[j]);  B1[j + 4] = (short)f2bf(xa3[j]);
        }

        f32x4 acc[4] = {f32x4{}, f32x4{}, f32x4{}, f32x4{}};
#pragma unroll
        for (int ft = 0; ft < 4; ++ft) {
            acc[ft] = __builtin_amdgcn_mfma_f32_16x16x32_bf16(wfrag[ft][0], B0, acc[ft], 0, 0, 0);
            acc[ft] = __builtin_amdgcn_mfma_f32_16x16x32_bf16(wfrag[ft][1], B1, acc[ft], 0, 0, 0);
        }

        // D[f][c] -> LDS bf16 tile at [c_local=fl][f_glob=rel*64+ft*16+kgrp*4+i]
        char* tb = tile0 + b * 16384;
#pragma unroll
        for (int ft = 0; ft < 4; ++ft) {
            ushort4 o;
            o.x = f2bf(acc[ft][0]); o.y = f2bf(acc[ft][1]);
            o.z = f2bf(acc[ft][2]); o.w = f2bf(acc[ft][3]);
            *reinterpret_cast<ushort4*>(tb + ((wbase + (ft << 5)) ^ wswz)) = o;
        }

        // raw barrier: wait LDS only, do NOT drain global stores (vmcnt)
        __builtin_amdgcn_sched_barrier(0);
        asm volatile("s_waitcnt lgkmcnt(0)" ::: "memory");
        __builtin_amdgcn_s_barrier();
        __builtin_amdgcn_sched_barrier(0);

        // stream tile -> y, coalesced 16B/lane, nontemporal fire-and-forget
#pragma unroll
        for (int h = 0; h < 2; ++h) {
            int u  = t + h * 512;              // 16B unit 0..1023
            int cl = u >> 6;                   // c_local
            i32x4 v = *reinterpret_cast<const i32x4*>(tb + ((u << 4) ^ ((cl & 7) << 4)));
            __builtin_nontemporal_store(v, reinterpret_cast<i32x4*>(
                y + (size_t)(strip * 16 + cl) * YDIM + ((u & 63) << 3)));
        }
        b ^= 1;   // buffer reuse at distance 2 is protected by the barrier chain
        xa0 = xn0; xa1 = xn1; xa2 = xn2; xa3 = xn3;
        strip = next;
    }
}

// ---------------------------------------------------------------------------
// Gather (unchanged from round 20): block = one 98-node bucket, 1024 thr /
// 16 waves; (node,rel) CSR in LDS; 4x16-lane-group edge loop (4 y rows per
// wave instruction, unroll x2 -> 8 in flight); shfl_xor cross-group reduce;
// lanes 0-15 write a coalesced float4.
// ---------------------------------------------------------------------------
__global__ __launch_bounds__(1024) void k_gather(const int* __restrict__ cursor,
                                                 const int* __restrict__ keys,
                                                 const unsigned short* __restrict__ yb,
                                                 float* __restrict__ out) {
    __shared__ int srt[CAPB];
    __shared__ int cntL[1024], offL[1024], curL[1024];

    const int bkt  = blockIdx.x;
    const int tid  = threadIdx.x;
    const int lane = tid & 63;
    const int wid  = tid >> 6;

    const int s0 = bkt * CAPB;
    int m = cursor[bkt] - s0;             // count (cursor = region end)
    if (m > CAPB) m = CAPB;               // overflow guard (+9.7 sigma, ~never)

    cntL[tid] = 0;
    __syncthreads();

    for (int i = tid; i < m; i += 1024) {
        int k = keys[s0 + i];
        atomicAdd(&cntL[((k >> 20) << 3) | (k & 7)], 1);
    }
    __syncthreads();

    if (wid == 0) {                        // exclusive scan of 1024 counters
        int c16[16], pre16[16], run = 0;
#pragma unroll
        for (int j = 0; j < 16; ++j) {
            c16[j] = cntL[lane * 16 + j];
            pre16[j] = run; run += c16[j];
        }
        int ex = run;
#pragma unroll
        for (int d = 1; d < 64; d <<= 1) { int u = __shfl_up(ex, d); if (lane >= d) ex += u; }
        ex -= run;
#pragma unroll
        for (int j = 0; j < 16; ++j) {
            offL[lane * 16 + j] = ex + pre16[j];
            curL[lane * 16 + j] = ex + pre16[j];
        }
    }
    __syncthreads();

    for (int i = tid; i < m; i += 1024) {
        int k = keys[s0 + i];
        int p = atomicAdd(&curL[((k >> 20) << 3) | (k & 7)], 1);
        srt[p] = k;
    }
    __syncthreads();

    const int nbase = bkt * GNODES;
    int nlim = NNODES - nbase; if (nlim > GNODES) nlim = GNODES;
    const int grp  = lane >> 4;            // 0..3: edge group
    const int fpos = lane & 15;            // 4 f-values per lane

    for (int i = wid; i < nlim; i += 16) {
        const int b8 = i << 3;
        int myc = cntL[b8 + (lane & 7)];                  // lane L: cnt of rel L&7
        float invv = (myc > 0) ? __builtin_amdgcn_rcpf((float)myc) : 0.f;
        int invb = __float_as_int(invv);

        int s = offL[b8];
        int e = offL[b8 + 7] + cntL[b8 + 7];
        int d = e - s; if (d > 64) d = 64;                // Poisson(10) safety
        int kv = (lane < d) ? srt[s + lane] : 0;

        f32x4 accA = {}, accB = {};
        for (int j0 = 0; j0 < d; j0 += 8) {
            int ja = j0 + grp, jb = j0 + 4 + grp;
            int jca = ja < d ? ja : 0;
            int jcb = jb < d ? jb : 0;
            int ka = __shfl(kv, jca);                     // group-uniform key
            int kb = __shfl(kv, jcb);
            const ushort4 va = *reinterpret_cast<const ushort4*>(
                yb + (size_t)((ka >> 3) & 0x1FFFF) * YDIM + (ka & 7) * EMB + fpos * 4);
            const ushort4 vb = *reinterpret_cast<const ushort4*>(
                yb + (size_t)((kb >> 3) & 0x1FFFF) * YDIM + (kb & 7) * EMB + fpos * 4);
            float sia = (ja < d) ? __int_as_float(__shfl(invb, ka & 7)) : 0.f;
            float sib = (jb < d) ? __int_as_float(__shfl(invb, kb & 7)) : 0.f;
            accA[0] = fmaf(sia, bf2f(va.x), accA[0]);
            accA[1] = fmaf(sia, bf2f(va.y), accA[1]);
            accA[2] = fmaf(sia, bf2f(va.z), accA[2]);
            accA[3] = fmaf(sia, bf2f(va.w), accA[3]);
            accB[0] = fmaf(sib, bf2f(vb.x), accB[0]);
            accB[1] = fmaf(sib, bf2f(vb.y), accB[1]);
            accB[2] = fmaf(sib, bf2f(vb.z), accB[2]);
            accB[3] = fmaf(sib, bf2f(vb.w), accB[3]);
        }

        f32x4 acc;
#pragma unroll
        for (int q = 0; q < 4; ++q) acc[q] = accA[q] + accB[q];
#pragma unroll
        for (int q = 0; q < 4; ++q) acc[q] += __shfl_xor(acc[q], 16);
#pragma unroll
        for (int q = 0; q < 4; ++q) acc[q] += __shfl_xor(acc[q], 32);

        if (grp == 0) {
            f32x4 o;
#pragma unroll
            for (int q = 0; q < 4; ++q) o[q] = fmaxf(acc[q], 0.f);
            *reinterpret_cast<f32x4*>(out + (size_t)(nbase + i) * EMB + fpos * 4) = o;
        }
    }
}

// ---------------------------------------------------------------------------
extern "C" void kernel_launch(void* const* d_in, const int* in_sizes, int n_in,
                              void* d_out, int out_size, void* d_ws, size_t ws_size,
                              hipStream_t stream) {
    const float* x    = (const float*)d_in[0];
    const float* w    = (const float*)d_in[1];
    const int*   rows = (const int*)d_in[2];   // JAX x64-disabled -> int32
    const int*   cols = (const int*)d_in[3];
    float*       out  = (float*)d_out;
    int E = in_sizes[2];

    char* ws = (char*)d_ws;
    int*            cursor = (int*)(ws);                       // 4 KB region
    int*            keys   = (int*)(ws + 4096);                // 5.24 MB
    unsigned short* wp     = (unsigned short*)(ws + 5247232);  // 64 KB
    unsigned short* y      = (unsigned short*)(ws + 5313024);  // 102.4 MB

    int sblk = (E + SCHUNK - 1) / SCHUNK;     // 489 scatter blocks, dispatched first
    k_init<<<4, 256, 0, stream>>>(cursor);
    k_wprep<<<16, 256, 0, stream>>>(w, wp);
    k_main<<<sblk + GEMMB, 512, 0, stream>>>(rows, cols, cursor, keys, x, wp, y, E, sblk);
    k_gather<<<NBUCK, 1024, 0, stream>>>(cursor, keys, y, out);
}

// Round 22
// 95.417 us; speedup vs baseline: 1.1355x; 1.1355x over previous
//
#include <hip/hip_runtime.h>

#define NNODES 100000
#define NREL 8
#define EMB 64
#define YDIM (NREL * EMB)            // 512
#define NSTRIPS (NNODES / 16)        // 6250, exact
#define G1_BLOCKS 1250               // 5 strips per block, exact
#define GNODES 128                   // nodes per coarse bucket
#define NBUCK 782                    // ceil(NNODES/128)
#define CHUNK 4096                   // edges per scatter block
#define CAPB 1600                    // slots per bucket; lambda=1280, +9 sigma

typedef __attribute__((ext_vector_type(8))) short bf16x8;   // 8 bf16 (4 VGPRs)
typedef __attribute__((ext_vector_type(4))) float f32x4;
typedef __attribute__((ext_vector_type(4))) int   i32x4;    // for nontemporal 16B

__device__ inline unsigned short f2bf(float f) {
    union { float f; unsigned u; } v; v.f = f;
    return (unsigned short)((v.u + 0x7FFFu + ((v.u >> 16) & 1u)) >> 16);  // RNE
}
__device__ inline float bf2f(unsigned short u) {
    union { unsigned u; float f; } v; v.u = ((unsigned)u) << 16; return v.f;
}

// ---------------------------------------------------------------------------
// W prep + cursor init (k_init folded in; 4096 threads total).
// wp[t*8+j] = bf16(W[rel][ks*32+kgrp*8+j][ft*16+fl]), t = rel*512+ft*128+ks*64+lane
// ---------------------------------------------------------------------------
__global__ void k_wprep(const float* __restrict__ W, unsigned short* __restrict__ wp,
                        int* __restrict__ cursor) {
    int t = blockIdx.x * blockDim.x + threadIdx.x;   // 0..4095
    if (t < NBUCK) cursor[t] = t * CAPB;
    int lane = t & 63, ks = (t >> 6) & 1, ft = (t >> 7) & 3, rel = t >> 9;
    const float* src = W + rel * 4096 + (ks * 32 + (lane >> 4) * 8) * EMB
                       + ft * 16 + (lane & 15);
    bf16x8 o;
#pragma unroll
    for (int j = 0; j < 8; ++j) o[j] = (short)f2bf(src[j * EMB]);
    *reinterpret_cast<bf16x8*>(wp + (size_t)t * 8) = o;
}

// ---------------------------------------------------------------------------
// Partitioned scatter. Block = 4096 edges: LDS hist -> 2-BARRIER SHFL SCAN
// (was a 20-barrier ladder) -> one reserve atomic per (block,bucket) ->
// stage (key,delta) partitioned in LDS -> dense copy-out.
// Key = c<<3 | r | nloc<<20  (c<2^17, nloc = n&127).
// ---------------------------------------------------------------------------
__global__ __launch_bounds__(1024) void k_scatter2(const int* __restrict__ rows,
                                                   const int* __restrict__ cols,
                                                   int* __restrict__ cursor,
                                                   int* __restrict__ keys, int E) {
    __shared__ int hist[1024];            // bins 782..1023 stay zero
    __shared__ int loff[NBUCK];
    __shared__ int dlt[NBUCK];
    __shared__ int cur[NBUCK];
    __shared__ int part[16];
    __shared__ int2 stg[CHUNK];
    const int t = threadIdx.x;
    const int lane = t & 63;
    const int wid  = t >> 6;
    const int base = blockIdx.x * CHUNK;
    int m = E - base; if (m > CHUNK) m = CHUNK;

    hist[t] = 0;
    if (t < NBUCK) cur[t] = 0;
    __syncthreads();

    int key[4], bk[4];
#pragma unroll
    for (int q = 0; q < 4; ++q) {
        int i = t + q * 1024;
        bk[q] = -1;
        if (i < m) {
            int row = rows[base + i];
            int c   = cols[base + i];
            int r = row / NNODES;            // magic-mul
            int n = row - r * NNODES;
            bk[q]  = n >> 7;
            key[q] = (c << 3) | r | ((n & 127) << 20);
            atomicAdd(&hist[bk[q]], 1);
        }
    }
    __syncthreads();

    // 2-barrier exclusive scan over 1024 bins (wave shfl-scan + 16 partials)
    int v = hist[t];
    int inc = v;
#pragma unroll
    for (int d = 1; d < 64; d <<= 1) { int u = __shfl_up(inc, d); if (lane >= d) inc += u; }
    if (lane == 63) part[wid] = inc;
    __syncthreads();
    int woff = 0;
    for (int i = 0; i < wid; ++i) woff += part[i];
    int excl = woff + inc - v;
    if (t < NBUCK) {
        loff[t] = excl;
        int gb = (v > 0) ? atomicAdd(&cursor[t], v) : 0;
        dlt[t] = gb - excl;
    }
    __syncthreads();

#pragma unroll
    for (int q = 0; q < 4; ++q) {
        if (bk[q] >= 0) {
            int p = loff[bk[q]] + atomicAdd(&cur[bk[q]], 1);
            stg[p] = make_int2(key[q], dlt[bk[q]]);
        }
    }
    __syncthreads();

    for (int i = t; i < m; i += 1024) {
        int2 s = stg[i];
        keys[s.y + i] = s.x;
    }
}

// ---------------------------------------------------------------------------
// GEMM1 (unchanged from round 19): y[c, r*64+f] = sum_k x[c,k] * W[r,k,f],
// nontemporal y stores. At the ~2.2-2.4 TB/s pure-write ceiling (measured
// invariant across 3 store schemes) -> structural floor ~43us for 100MB.
// ---------------------------------------------------------------------------
__global__ __launch_bounds__(512) void k_gemm1(const float* __restrict__ x,
                                               const unsigned short* __restrict__ wp,
                                               unsigned short* __restrict__ y) {
    __shared__ char tile[2][16384];        // bf16 [16][512], swizzled, x2 buffers
    const int tid  = threadIdx.x;
    const int lane = tid & 63;
    const int rel  = tid >> 6;             // wave id = relation
    const int fl   = lane & 15;            // A row (f_local) == B col (c_local)
    const int kgrp = lane >> 4;            // k-group 0..3

    bf16x8 wfrag[4][2];
#pragma unroll
    for (int ft = 0; ft < 4; ++ft)
#pragma unroll
        for (int ks = 0; ks < 2; ++ks)
            wfrag[ft][ks] = *reinterpret_cast<const bf16x8*>(
                wp + (size_t)((rel * 4 + ft) * 2 + ks) * 512 + lane * 8);

    const int wbase = (fl << 10) + (rel << 7) + (kgrp << 3);
    const int wswz  = (fl & 7) << 4;
    int b = 0;

    int strip = blockIdx.x;
    const float* xp = x + (size_t)(strip * 16 + fl) * EMB + kgrp * 8;
    f32x4 xa0 = *reinterpret_cast<const f32x4*>(xp);
    f32x4 xa1 = *reinterpret_cast<const f32x4*>(xp + 4);
    f32x4 xa2 = *reinterpret_cast<const f32x4*>(xp + 32);
    f32x4 xa3 = *reinterpret_cast<const f32x4*>(xp + 36);

    while (strip < NSTRIPS) {
        const int next = strip + G1_BLOCKS;
        f32x4 xn0 = xa0, xn1 = xa1, xn2 = xa2, xn3 = xa3;
        if (next < NSTRIPS) {              // prefetch next strip's x rows
            const float* xq = x + (size_t)(next * 16 + fl) * EMB + kgrp * 8;
            xn0 = *reinterpret_cast<const f32x4*>(xq);
            xn1 = *reinterpret_cast<const f32x4*>(xq + 4);
            xn2 = *reinterpret_cast<const f32x4*>(xq + 32);
            xn3 = *reinterpret_cast<const f32x4*>(xq + 36);
        }

        bf16x8 B0, B1;
#pragma unroll
        for (int j = 0; j < 4; ++j) {
            B0[j] = (short)f2bf(xa0[j]);  B0[j + 4] = (short)f2bf(xa1[j]);
            B1[j] = (short)f2bf(xa2[j]);  B1[j + 4] = (short)f2bf(xa3[j]);
        }

        f32x4 acc[4] = {f32x4{}, f32x4{}, f32x4{}, f32x4{}};
#pragma unroll
        for (int ft = 0; ft < 4; ++ft) {
            acc[ft] = __builtin_amdgcn_mfma_f32_16x16x32_bf16(wfrag[ft][0], B0, acc[ft], 0, 0, 0);
            acc[ft] = __builtin_amdgcn_mfma_f32_16x16x32_bf16(wfrag[ft][1], B1, acc[ft], 0, 0, 0);
        }

        // D[f][c] -> LDS bf16 tile at [c_local=fl][f_glob=rel*64+ft*16+kgrp*4+i]
        char* tb = tile[b];
#pragma unroll
        for (int ft = 0; ft < 4; ++ft) {
            ushort4 o;
            o.x = f2bf(acc[ft][0]); o.y = f2bf(acc[ft][1]);
            o.z = f2bf(acc[ft][2]); o.w = f2bf(acc[ft][3]);
            *reinterpret_cast<ushort4*>(tb + ((wbase + (ft << 5)) ^ wswz)) = o;
        }

        // raw barrier: wait LDS only, do NOT drain global stores (vmcnt)
        __builtin_amdgcn_sched_barrier(0);
        asm volatile("s_waitcnt lgkmcnt(0)" ::: "memory");
        __builtin_amdgcn_s_barrier();
        __builtin_amdgcn_sched_barrier(0);

        // stream tile -> y, coalesced 16B/lane, nontemporal fire-and-forget
#pragma unroll
        for (int h = 0; h < 2; ++h) {
            int u  = tid + h * 512;            // 16B unit 0..1023
            int cl = u >> 6;                   // c_local
            i32x4 v = *reinterpret_cast<const i32x4*>(tb + ((u << 4) ^ ((cl & 7) << 4)));
            __builtin_nontemporal_store(v, reinterpret_cast<i32x4*>(
                y + (size_t)(strip * 16 + cl) * YDIM + ((u & 63) << 3)));
        }
        b ^= 1;   // buffer reuse at distance 2 is protected by the barrier chain
        xa0 = xn0; xa1 = xn1; xa2 = xn2; xa3 = xn3;
        strip = next;
    }
}

// ---------------------------------------------------------------------------
// Gather: block = one 128-node bucket, 1024 thr / 16 waves; (node,rel) CSR in
// LDS. Edge loop: 4x16-lane groups, 16-DEEP unroll (4 accumulators) -> 16
// distinct y rows in flight per wave (was 8). shfl_xor cross-group reduce;
// lanes 0-15 write a coalesced float4.
// ---------------------------------------------------------------------------
__global__ __launch_bounds__(1024) void k_gather(const int* __restrict__ cursor,
                                                 const int* __restrict__ keys,
                                                 const unsigned short* __restrict__ yb,
                                                 float* __restrict__ out) {
    __shared__ int srt[CAPB];
    __shared__ int cntL[1024], offL[1024], curL[1024];

    const int bkt  = blockIdx.x;
    const int tid  = threadIdx.x;
    const int lane = tid & 63;
    const int wid  = tid >> 6;

    const int s0 = bkt * CAPB;
    int m = cursor[bkt] - s0;             // count (cursor = region end)
    if (m > CAPB) m = CAPB;               // overflow guard (+9 sigma, ~never)

    cntL[tid] = 0;
    __syncthreads();

    for (int i = tid; i < m; i += 1024) {
        int k = keys[s0 + i];
        atomicAdd(&cntL[((k >> 20) << 3) | (k & 7)], 1);
    }
    __syncthreads();

    if (wid == 0) {                        // exclusive scan of 1024 counters
        int c16[16], pre16[16], run = 0;
#pragma unroll
        for (int j = 0; j < 16; ++j) {
            c16[j] = cntL[lane * 16 + j];
            pre16[j] = run; run += c16[j];
        }
        int ex = run;
#pragma unroll
        for (int d = 1; d < 64; d <<= 1) { int u = __shfl_up(ex, d); if (lane >= d) ex += u; }
        ex -= run;
#pragma unroll
        for (int j = 0; j < 16; ++j) {
            offL[lane * 16 + j] = ex + pre16[j];
            curL[lane * 16 + j] = ex + pre16[j];
        }
    }
    __syncthreads();

    for (int i = tid; i < m; i += 1024) {
        int k = keys[s0 + i];
        int p = atomicAdd(&curL[((k >> 20) << 3) | (k & 7)], 1);
        srt[p] = k;
    }
    __syncthreads();

    const int nbase = bkt * GNODES;
    int nlim = NNODES - nbase; if (nlim > GNODES) nlim = GNODES;
    const int grp  = lane >> 4;            // 0..3: edge group
    const int fpos = lane & 15;            // 4 f-values per lane

    for (int i = wid; i < nlim; i += 16) {
        const int b8 = i << 3;
        int myc = cntL[b8 + (lane & 7)];                  // lane L: cnt of rel L&7
        float invv = (myc > 0) ? __builtin_amdgcn_rcpf((float)myc) : 0.f;
        int invb = __float_as_int(invv);

        int s = offL[b8];
        int e = offL[b8 + 7] + cntL[b8 + 7];
        int d = e - s; if (d > 64) d = 64;                // Poisson(10) safety
        int kv = (lane < d) ? srt[s + lane] : 0;

        f32x4 accA = {}, accB = {}, accC = {}, accD = {};
        for (int j0 = 0; j0 < d; j0 += 16) {
            int ja = j0 + grp, jb = j0 + 4 + grp, jc = j0 + 8 + grp, jd = j0 + 12 + grp;
            int ca = ja < d ? ja : 0, cb = jb < d ? jb : 0;
            int cc = jc < d ? jc : 0, cd = jd < d ? jd : 0;
            int ka = __shfl(kv, ca), kb = __shfl(kv, cb);
            int kc = __shfl(kv, cc), kd = __shfl(kv, cd);
            const ushort4 va = *reinterpret_cast<const ushort4*>(
                yb + (size_t)((ka >> 3) & 0x1FFFF) * YDIM + (ka & 7) * EMB + fpos * 4);
            const ushort4 vb = *reinterpret_cast<const ushort4*>(
                yb + (size_t)((kb >> 3) & 0x1FFFF) * YDIM + (kb & 7) * EMB + fpos * 4);
            const ushort4 vc = *reinterpret_cast<const ushort4*>(
                yb + (size_t)((kc >> 3) & 0x1FFFF) * YDIM + (kc & 7) * EMB + fpos * 4);
            const ushort4 vd = *reinterpret_cast<const ushort4*>(
                yb + (size_t)((kd >> 3) & 0x1FFFF) * YDIM + (kd & 7) * EMB + fpos * 4);
            float sia = (ja < d) ? __int_as_float(__shfl(invb, ka & 7)) : 0.f;
            float sib = (jb < d) ? __int_as_float(__shfl(invb, kb & 7)) : 0.f;
            float sic = (jc < d) ? __int_as_float(__shfl(invb, kc & 7)) : 0.f;
            float sid = (jd < d) ? __int_as_float(__shfl(invb, kd & 7)) : 0.f;
            accA[0] = fmaf(sia, bf2f(va.x), accA[0]);
            accA[1] = fmaf(sia, bf2f(va.y), accA[1]);
            accA[2] = fmaf(sia, bf2f(va.z), accA[2]);
            accA[3] = fmaf(sia, bf2f(va.w), accA[3]);
            accB[0] = fmaf(sib, bf2f(vb.x), accB[0]);
            accB[1] = fmaf(sib, bf2f(vb.y), accB[1]);
            accB[2] = fmaf(sib, bf2f(vb.z), accB[2]);
            accB[3] = fmaf(sib, bf2f(vb.w), accB[3]);
            accC[0] = fmaf(sic, bf2f(vc.x), accC[0]);
            accC[1] = fmaf(sic, bf2f(vc.y), accC[1]);
            accC[2] = fmaf(sic, bf2f(vc.z), accC[2]);
            accC[3] = fmaf(sic, bf2f(vc.w), accC[3]);
            accD[0] = fmaf(sid, bf2f(vd.x), accD[0]);
            accD[1] = fmaf(sid, bf2f(vd.y), accD[1]);
            accD[2] = fmaf(sid, bf2f(vd.z), accD[2]);
            accD[3] = fmaf(sid, bf2f(vd.w), accD[3]);
        }

        f32x4 acc;
#pragma unroll
        for (int q = 0; q < 4; ++q) acc[q] = (accA[q] + accB[q]) + (accC[q] + accD[q]);
#pragma unroll
        for (int q = 0; q < 4; ++q) acc[q] += __shfl_xor(acc[q], 16);
#pragma unroll
        for (int q = 0; q < 4; ++q) acc[q] += __shfl_xor(acc[q], 32);

        if (grp == 0) {
            f32x4 o;
#pragma unroll
            for (int q = 0; q < 4; ++q) o[q] = fmaxf(acc[q], 0.f);
            *reinterpret_cast<f32x4*>(out + (size_t)(nbase + i) * EMB + fpos * 4) = o;
        }
    }
}

// ---------------------------------------------------------------------------
extern "C" void kernel_launch(void* const* d_in, const int* in_sizes, int n_in,
                              void* d_out, int out_size, void* d_ws, size_t ws_size,
                              hipStream_t stream) {
    const float* x    = (const float*)d_in[0];
    const float* w    = (const float*)d_in[1];
    const int*   rows = (const int*)d_in[2];   // JAX x64-disabled -> int32
    const int*   cols = (const int*)d_in[3];
    float*       out  = (float*)d_out;
    int E = in_sizes[2];

    char* ws = (char*)d_ws;
    int*            cursor = (int*)(ws);                       // 4 KB region
    int*            keys   = (int*)(ws + 4096);                // 5.0 MB
    unsigned short* wp     = (unsigned short*)(ws + 5126144);  // 64 KB
    unsigned short* y      = (unsigned short*)(ws + 5191680);  // 102.4 MB

    int eb = (E + CHUNK - 1) / CHUNK;     // 245
    k_wprep<<<16, 256, 0, stream>>>(w, wp, cursor);
    k_scatter2<<<eb, 1024, 0, stream>>>(rows, cols, cursor, keys, E);
    k_gemm1<<<G1_BLOCKS, 512, 0, stream>>>(x, wp, y);
    k_gather<<<NBUCK, 1024, 0, stream>>>(cursor, keys, y, out);
}

// Round 23
// 92.765 us; speedup vs baseline: 1.1679x; 1.0286x over previous
//
#include <hip/hip_runtime.h>

#define NNODES 100000
#define NREL 8
#define EMB 64
#define YDIM (NREL * EMB)            // 512
#define NSTRIPS (NNODES / 16)        // 6250, exact
#define G1_BLOCKS 1250               // 5 strips per block, exact
#define GNODES 128                   // nodes per coarse bucket
#define NBUCK 782                    // ceil(NNODES/128)
#define CHUNK 4096                   // edges per scatter block
#define CAPB 1600                    // slots per bucket; lambda=1280, +9 sigma

typedef __attribute__((ext_vector_type(8))) short bf16x8;   // 8 bf16 (4 VGPRs)
typedef __attribute__((ext_vector_type(4))) float f32x4;
typedef __attribute__((ext_vector_type(4))) int   i32x4;    // for nontemporal 16B

__device__ inline unsigned short f2bf(float f) {
    union { float f; unsigned u; } v; v.f = f;
    return (unsigned short)((v.u + 0x7FFFu + ((v.u >> 16) & 1u)) >> 16);  // RNE
}
__device__ inline float bf2f(unsigned short u) {
    union { unsigned u; float f; } v; v.u = ((unsigned)u) << 16; return v.f;
}

// ---------------------------------------------------------------------------
// W prep + cursor init (4096 threads total).
// wp[t*8+j] = bf16(W[rel][ks*32+kgrp*8+j][ft*16+fl]), t = rel*512+ft*128+ks*64+lane
// ---------------------------------------------------------------------------
__global__ void k_wprep(const float* __restrict__ W, unsigned short* __restrict__ wp,
                        int* __restrict__ cursor) {
    int t = blockIdx.x * blockDim.x + threadIdx.x;   // 0..4095
    if (t < NBUCK) cursor[t] = t * CAPB;
    int lane = t & 63, ks = (t >> 6) & 1, ft = (t >> 7) & 3, rel = t >> 9;
    const float* src = W + rel * 4096 + (ks * 32 + (lane >> 4) * 8) * EMB
                       + ft * 16 + (lane & 15);
    bf16x8 o;
#pragma unroll
    for (int j = 0; j < 8; ++j) o[j] = (short)f2bf(src[j * EMB]);
    *reinterpret_cast<bf16x8*>(wp + (size_t)t * 8) = o;
}

// ---------------------------------------------------------------------------
// Partitioned scatter (unchanged from round 22): LDS hist -> 2-barrier shfl
// scan -> one reserve atomic per (block,bucket) -> staged dense copy-out.
// Key = c<<3 | r | nloc<<20  (c<2^17, nloc = n&127).
// ---------------------------------------------------------------------------
__global__ __launch_bounds__(1024) void k_scatter2(const int* __restrict__ rows,
                                                   const int* __restrict__ cols,
                                                   int* __restrict__ cursor,
                                                   int* __restrict__ keys, int E) {
    __shared__ int hist[1024];            // bins 782..1023 stay zero
    __shared__ int loff[NBUCK];
    __shared__ int dlt[NBUCK];
    __shared__ int cur[NBUCK];
    __shared__ int part[16];
    __shared__ int2 stg[CHUNK];
    const int t = threadIdx.x;
    const int lane = t & 63;
    const int wid  = t >> 6;
    const int base = blockIdx.x * CHUNK;
    int m = E - base; if (m > CHUNK) m = CHUNK;

    hist[t] = 0;
    if (t < NBUCK) cur[t] = 0;
    __syncthreads();

    int key[4], bk[4];
#pragma unroll
    for (int q = 0; q < 4; ++q) {
        int i = t + q * 1024;
        bk[q] = -1;
        if (i < m) {
            int row = rows[base + i];
            int c   = cols[base + i];
            int r = row / NNODES;            // magic-mul
            int n = row - r * NNODES;
            bk[q]  = n >> 7;
            key[q] = (c << 3) | r | ((n & 127) << 20);
            atomicAdd(&hist[bk[q]], 1);
        }
    }
    __syncthreads();

    // 2-barrier exclusive scan over 1024 bins (wave shfl-scan + 16 partials)
    int v = hist[t];
    int inc = v;
#pragma unroll
    for (int d = 1; d < 64; d <<= 1) { int u = __shfl_up(inc, d); if (lane >= d) inc += u; }
    if (lane == 63) part[wid] = inc;
    __syncthreads();
    int woff = 0;
    for (int i = 0; i < wid; ++i) woff += part[i];
    int excl = woff + inc - v;
    if (t < NBUCK) {
        loff[t] = excl;
        int gb = (v > 0) ? atomicAdd(&cursor[t], v) : 0;
        dlt[t] = gb - excl;
    }
    __syncthreads();

#pragma unroll
    for (int q = 0; q < 4; ++q) {
        if (bk[q] >= 0) {
            int p = loff[bk[q]] + atomicAdd(&cur[bk[q]], 1);
            stg[p] = make_int2(key[q], dlt[bk[q]]);
        }
    }
    __syncthreads();

    for (int i = t; i < m; i += 1024) {
        int2 s = stg[i];
        keys[s.y + i] = s.x;
    }
}

// ---------------------------------------------------------------------------
// GEMM1, WAVE-DECOUPLED: y[c, r*64+f] = sum_k x[c,k] * W[r,k,f].
// Wave = relation owns a disjoint 128B band of each y row -> no cross-wave
// data. Each wave has a PRIVATE 2KB LDS tile (x2 buffers): D fragments go in
// as swizzled 8B ds_write, come out as 16B units, 2 nontemporal 16B stores
// per lane (16 rows x 64B full-line segments). ZERO barriers in the loop --
// wave-local lgkmcnt ordering suffices; waves free-run so the y store stream
// is continuous, not barrier-burst (tests the 2.4 TB/s ceiling hypothesis).
// ---------------------------------------------------------------------------
__global__ __launch_bounds__(512) void k_gemm1(const float* __restrict__ x,
                                               const unsigned short* __restrict__ wp,
                                               unsigned short* __restrict__ y) {
    __shared__ char tiles[8][2][2048];     // per-wave private, double-buffered
    const int tid  = threadIdx.x;
    const int lane = tid & 63;
    const int rel  = tid >> 6;             // wave id = relation
    const int fl   = lane & 15;            // A row (f_local) == B col (c_local)
    const int kgrp = lane >> 4;            // k-group 0..3

    bf16x8 wfrag[4][2];
#pragma unroll
    for (int ft = 0; ft < 4; ++ft)
#pragma unroll
        for (int ks = 0; ks < 2; ++ks)
            wfrag[ft][ks] = *reinterpret_cast<const bf16x8*>(
                wp + (size_t)((rel * 4 + ft) * 2 + ks) * 512 + lane * 8);

    // write-side addressing: row fl, 16B unit v = ft*2+(kgrp>>1) swizzled by fl
    const int wrow  = fl << 7;             // fl * 128
    const int wswz  = fl & 7;
    const int whalf = (kgrp & 1) << 3;
    // read-side: lane covers c = lane>>2, units u and u+4
    const int rc  = lane >> 2;
    const int ru  = lane & 3;
    const int rbyte0 = (rc << 7) + (((ru)     ^ (rc & 7)) << 4);
    const int rbyte1 = (rc << 7) + (((ru + 4) ^ (rc & 7)) << 4);
    int b = 0;

    int strip = blockIdx.x;
    const float* xp = x + (size_t)(strip * 16 + fl) * EMB + kgrp * 8;
    f32x4 xa0 = *reinterpret_cast<const f32x4*>(xp);
    f32x4 xa1 = *reinterpret_cast<const f32x4*>(xp + 4);
    f32x4 xa2 = *reinterpret_cast<const f32x4*>(xp + 32);
    f32x4 xa3 = *reinterpret_cast<const f32x4*>(xp + 36);

    while (strip < NSTRIPS) {
        const int next = strip + G1_BLOCKS;
        f32x4 xn0 = xa0, xn1 = xa1, xn2 = xa2, xn3 = xa3;
        if (next < NSTRIPS) {              // prefetch next strip's x rows
            const float* xq = x + (size_t)(next * 16 + fl) * EMB + kgrp * 8;
            xn0 = *reinterpret_cast<const f32x4*>(xq);
            xn1 = *reinterpret_cast<const f32x4*>(xq + 4);
            xn2 = *reinterpret_cast<const f32x4*>(xq + 32);
            xn3 = *reinterpret_cast<const f32x4*>(xq + 36);
        }

        bf16x8 B0, B1;
#pragma unroll
        for (int j = 0; j < 4; ++j) {
            B0[j] = (short)f2bf(xa0[j]);  B0[j + 4] = (short)f2bf(xa1[j]);
            B1[j] = (short)f2bf(xa2[j]);  B1[j + 4] = (short)f2bf(xa3[j]);
        }

        f32x4 acc[4] = {f32x4{}, f32x4{}, f32x4{}, f32x4{}};
#pragma unroll
        for (int ft = 0; ft < 4; ++ft) {
            acc[ft] = __builtin_amdgcn_mfma_f32_16x16x32_bf16(wfrag[ft][0], B0, acc[ft], 0, 0, 0);
            acc[ft] = __builtin_amdgcn_mfma_f32_16x16x32_bf16(wfrag[ft][1], B1, acc[ft], 0, 0, 0);
        }

        // D[f][c] -> private tile: row c=fl, 8B at swizzled 16B unit
        char* tb = tiles[rel][b];
#pragma unroll
        for (int ft = 0; ft < 4; ++ft) {
            ushort4 o;
            o.x = f2bf(acc[ft][0]); o.y = f2bf(acc[ft][1]);
            o.z = f2bf(acc[ft][2]); o.w = f2bf(acc[ft][3]);
            int v = (ft << 1) + (kgrp >> 1);
            *reinterpret_cast<ushort4*>(tb + wrow + ((v ^ wswz) << 4) + whalf) = o;
        }

        // read back 2x16B (wave-local lgkmcnt dependency; no barrier) and
        // stream to y: 16 rows x 64B full-line segments, nontemporal
        i32x4 v0 = *reinterpret_cast<const i32x4*>(tb + rbyte0);
        i32x4 v1 = *reinterpret_cast<const i32x4*>(tb + rbyte1);
        unsigned short* yp = y + (size_t)(strip * 16 + rc) * YDIM + rel * EMB + ru * 8;
        __builtin_nontemporal_store(v0, reinterpret_cast<i32x4*>(yp));
        __builtin_nontemporal_store(v1, reinterpret_cast<i32x4*>(yp + 32));

        b ^= 1;
        xa0 = xn0; xa1 = xn1; xa2 = xn2; xa3 = xn3;
        strip = next;
    }
}

// ---------------------------------------------------------------------------
// Gather (unchanged from round 22): block = one 128-node bucket, 1024 thr /
// 16 waves; (node,rel) CSR in LDS; 4x16-lane groups, 16-deep unroll -> 16
// distinct y rows in flight per wave; shfl_xor cross-group reduce; lanes
// 0-15 write a coalesced float4.
// ---------------------------------------------------------------------------
__global__ __launch_bounds__(1024) void k_gather(const int* __restrict__ cursor,
                                                 const int* __restrict__ keys,
                                                 const unsigned short* __restrict__ yb,
                                                 float* __restrict__ out) {
    __shared__ int srt[CAPB];
    __shared__ int cntL[1024], offL[1024], curL[1024];

    const int bkt  = blockIdx.x;
    const int tid  = threadIdx.x;
    const int lane = tid & 63;
    const int wid  = tid >> 6;

    const int s0 = bkt * CAPB;
    int m = cursor[bkt] - s0;             // count (cursor = region end)
    if (m > CAPB) m = CAPB;               // overflow guard (+9 sigma, ~never)

    cntL[tid] = 0;
    __syncthreads();

    for (int i = tid; i < m; i += 1024) {
        int k = keys[s0 + i];
        atomicAdd(&cntL[((k >> 20) << 3) | (k & 7)], 1);
    }
    __syncthreads();

    if (wid == 0) {                        // exclusive scan of 1024 counters
        int c16[16], pre16[16], run = 0;
#pragma unroll
        for (int j = 0; j < 16; ++j) {
            c16[j] = cntL[lane * 16 + j];
            pre16[j] = run; run += c16[j];
        }
        int ex = run;
#pragma unroll
        for (int d = 1; d < 64; d <<= 1) { int u = __shfl_up(ex, d); if (lane >= d) ex += u; }
        ex -= run;
#pragma unroll
        for (int j = 0; j < 16; ++j) {
            offL[lane * 16 + j] = ex + pre16[j];
            curL[lane * 16 + j] = ex + pre16[j];
        }
    }
    __syncthreads();

    for (int i = tid; i < m; i += 1024) {
        int k = keys[s0 + i];
        int p = atomicAdd(&curL[((k >> 20) << 3) | (k & 7)], 1);
        srt[p] = k;
    }
    __syncthreads();

    const int nbase = bkt * GNODES;
    int nlim = NNODES - nbase; if (nlim > GNODES) nlim = GNODES;
    const int grp  = lane >> 4;            // 0..3: edge group
    const int fpos = lane & 15;            // 4 f-values per lane

    for (int i = wid; i < nlim; i += 16) {
        const int b8 = i << 3;
        int myc = cntL[b8 + (lane & 7)];                  // lane L: cnt of rel L&7
        float invv = (myc > 0) ? __builtin_amdgcn_rcpf((float)myc) : 0.f;
        int invb = __float_as_int(invv);

        int s = offL[b8];
        int e = offL[b8 + 7] + cntL[b8 + 7];
        int d = e - s; if (d > 64) d = 64;                // Poisson(10) safety
        int kv = (lane < d) ? srt[s + lane] : 0;

        f32x4 accA = {}, accB = {}, accC = {}, accD = {};
        for (int j0 = 0; j0 < d; j0 += 16) {
            int ja = j0 + grp, jb = j0 + 4 + grp, jc = j0 + 8 + grp, jd = j0 + 12 + grp;
            int ca = ja < d ? ja : 0, cb = jb < d ? jb : 0;
            int cc = jc < d ? jc : 0, cd = jd < d ? jd : 0;
            int ka = __shfl(kv, ca), kb = __shfl(kv, cb);
            int kc = __shfl(kv, cc), kd = __shfl(kv, cd);
            const ushort4 va = *reinterpret_cast<const ushort4*>(
                yb + (size_t)((ka >> 3) & 0x1FFFF) * YDIM + (ka & 7) * EMB + fpos * 4);
            const ushort4 vb = *reinterpret_cast<const ushort4*>(
                yb + (size_t)((kb >> 3) & 0x1FFFF) * YDIM + (kb & 7) * EMB + fpos * 4);
            const ushort4 vc = *reinterpret_cast<const ushort4*>(
                yb + (size_t)((kc >> 3) & 0x1FFFF) * YDIM + (kc & 7) * EMB + fpos * 4);
            const ushort4 vd = *reinterpret_cast<const ushort4*>(
                yb + (size_t)((kd >> 3) & 0x1FFFF) * YDIM + (kd & 7) * EMB + fpos * 4);
            float sia = (ja < d) ? __int_as_float(__shfl(invb, ka & 7)) : 0.f;
            float sib = (jb < d) ? __int_as_float(__shfl(invb, kb & 7)) : 0.f;
            float sic = (jc < d) ? __int_as_float(__shfl(invb, kc & 7)) : 0.f;
            float sid = (jd < d) ? __int_as_float(__shfl(invb, kd & 7)) : 0.f;
            accA[0] = fmaf(sia, bf2f(va.x), accA[0]);
            accA[1] = fmaf(sia, bf2f(va.y), accA[1]);
            accA[2] = fmaf(sia, bf2f(va.z), accA[2]);
            accA[3] = fmaf(sia, bf2f(va.w), accA[3]);
            accB[0] = fmaf(sib, bf2f(vb.x), accB[0]);
            accB[1] = fmaf(sib, bf2f(vb.y), accB[1]);
            accB[2] = fmaf(sib, bf2f(vb.z), accB[2]);
            accB[3] = fmaf(sib, bf2f(vb.w), accB[3]);
            accC[0] = fmaf(sic, bf2f(vc.x), accC[0]);
            accC[1] = fmaf(sic, bf2f(vc.y), accC[1]);
            accC[2] = fmaf(sic, bf2f(vc.z), accC[2]);
            accC[3] = fmaf(sic, bf2f(vc.w), accC[3]);
            accD[0] = fmaf(sid, bf2f(vd.x), accD[0]);
            accD[1] = fmaf(sid, bf2f(vd.y), accD[1]);
            accD[2] = fmaf(sid, bf2f(vd.z), accD[2]);
            accD[3] = fmaf(sid, bf2f(vd.w), accD[3]);
        }

        f32x4 acc;
#pragma unroll
        for (int q = 0; q < 4; ++q) acc[q] = (accA[q] + accB[q]) + (accC[q] + accD[q]);
#pragma unroll
        for (int q = 0; q < 4; ++q) acc[q] += __shfl_xor(acc[q], 16);
#pragma unroll
        for (int q = 0; q < 4; ++q) acc[q] += __shfl_xor(acc[q], 32);

        if (grp == 0) {
            f32x4 o;
#pragma unroll
            for (int q = 0; q < 4; ++q) o[q] = fmaxf(acc[q], 0.f);
            *reinterpret_cast<f32x4*>(out + (size_t)(nbase + i) * EMB + fpos * 4) = o;
        }
    }
}

// ---------------------------------------------------------------------------
extern "C" void kernel_launch(void* const* d_in, const int* in_sizes, int n_in,
                              void* d_out, int out_size, void* d_ws, size_t ws_size,
                              hipStream_t stream) {
    const float* x    = (const float*)d_in[0];
    const float* w    = (const float*)d_in[1];
    const int*   rows = (const int*)d_in[2];   // JAX x64-disabled -> int32
    const int*   cols = (const int*)d_in[3];
    float*       out  = (float*)d_out;
    int E = in_sizes[2];

    char* ws = (char*)d_ws;
    int*            cursor = (int*)(ws);                       // 4 KB region
    int*            keys   = (int*)(ws + 4096);                // 5.0 MB
    unsigned short* wp     = (unsigned short*)(ws + 5126144);  // 64 KB
    unsigned short* y      = (unsigned short*)(ws + 5191680);  // 102.4 MB

    int eb = (E + CHUNK - 1) / CHUNK;     // 245
    k_wprep<<<16, 256, 0, stream>>>(w, wp, cursor);
    k_scatter2<<<eb, 1024, 0, stream>>>(rows, cols, cursor, keys, E);
    k_gemm1<<<G1_BLOCKS, 512, 0, stream>>>(x, wp, y);
    k_gather<<<NBUCK, 1024, 0, stream>>>(cursor, keys, y, out);
}